// Round 16
// baseline (388.833 us; speedup 1.0000x reference)
//
#include <hip/hip_runtime.h>
#include <math.h>

#define NROWS 4096
#define MCOLS 16384
#define CDIM  256

typedef _Float16 half8 __attribute__((ext_vector_type(8)));
typedef float f32x4 __attribute__((ext_vector_type(4)));
typedef float f32x16 __attribute__((ext_vector_type(16)));

static __device__ __forceinline__ float softplusf(float x) {
    return fmaxf(x, 0.0f) + log1pf(expf(-fabsf(x)));
}

// Classic top-8 update (merge phases only)
#define TOPK_UPDATE(BV, BI, WORST, WP, V, IDX)                                 \
    if ((V) < (WORST)) {                                                       \
        BV[WP] = (V); BI[WP] = (IDX);                                          \
        WORST = BV[0]; WP = 0;                                                 \
        _Pragma("unroll")                                                      \
        for (int _q = 1; _q < 8; ++_q)                                         \
            if (BV[_q] > WORST) { WORST = BV[_q]; WP = _q; }                   \
    }

// Hot-loop top-8: slot index in 3 LSBs; worst via max-tree; gate = min(tau, worst).
#define TOPK_FAST(BV, BI, WORST, GATE, TAU, V, IDX)                            \
    if ((V) < (GATE)) {                                                        \
        const int _wp = __float_as_int(WORST) & 7;                             \
        BV[_wp] = __uint_as_float((__float_as_uint(V) & ~7u) | (unsigned)_wp); \
        BI[_wp] = (IDX);                                                       \
        const float _m0 = fmaxf(fmaxf(BV[0], BV[1]), fmaxf(BV[2], BV[3]));     \
        const float _m1 = fmaxf(fmaxf(BV[4], BV[5]), fmaxf(BV[6], BV[7]));     \
        WORST = fmaxf(_m0, _m1);                                               \
        GATE = fminf(TAU, WORST);                                              \
    }

// ---------------------------------------------------------------------------
// Passthrough copy
// ---------------------------------------------------------------------------
__global__ __launch_bounds__(256)
void copy_kernel(const float4* __restrict__ src, float4* __restrict__ dst, int n4) {
    int i = blockIdx.x * blockDim.x + threadIdx.x;
    if (i < n4) dst[i] = src[i];
}

// ---------------------------------------------------------------------------
// Column norms, fp32 tree (4 threads/column x 64 channels + shfl combine).
// ---------------------------------------------------------------------------
__global__ __launch_bounds__(256)
void norms_kernel(const float* __restrict__ xiT, const float* __restrict__ xpT,
                  float* __restrict__ normI, float* __restrict__ normP) {
    const int t = threadIdx.x;
    const int col = blockIdx.x * 64 + (t >> 2);
    const int sub = t & 3;
    const float* p;
    int base;
    if (col < MCOLS) { p = xpT; base = (col >> 12) * (CDIM * 4096) + (col & 4095); }
    else             { p = xiT; base = col - MCOLS; }
    float s = 0.0f;
#pragma unroll 8
    for (int k = 0; k < 64; ++k) {
        const float v = p[base + (sub * 64 + k) * 4096];
        s = fmaf(v, v, s);
    }
    s += __shfl_xor(s, 1);
    s += __shfl_xor(s, 2);
    if (sub == 0) {
        if (col < MCOLS) normP[col] = s;
        else             normI[col - MCOLS] = s;
    }
}

// ---------------------------------------------------------------------------
// fp32 [K=256][cols] -> fragment-ready fp16 hi/lo for 32x32x16 MFMA.
// Chunk (ct32*16 + kt)*64 + lane holds 8 halves:
//   element = x[col = ct32*32 + (lane&31)][k = kt*16 + (lane>>5)*8 + j]
// ---------------------------------------------------------------------------
__global__ __launch_bounds__(256)
void convert_kernel(const float* __restrict__ src, uint4* __restrict__ dhi,
                    uint4* __restrict__ dlo, int ncols) {
    __shared__ float S[64][65];
    const int t = threadIdx.x;
    const int tilesPerRow = ncols >> 6;
    const int colbase = (blockIdx.x % tilesPerRow) << 6;
    const int ktbase  = (blockIdx.x / tilesPerRow) << 6;
    const int b = colbase >> 12;
    const int pixbase = colbase & 4095;
    const float* sp = src + (size_t)b * (CDIM * 4096) + (size_t)ktbase * 4096 + pixbase;

    for (int i = t; i < 4096; i += 256) {
        int kk = i >> 6, cc = i & 63;
        S[kk][cc] = sp[kk * 4096 + cc];
    }
    __syncthreads();

    const int l = t & 63;
#pragma unroll
    for (int s = 0; s < 2; ++s) {
        const int pid  = (t >> 6) + 4 * s;   // 0..7
        const int ct_l = pid & 1;
        const int kt_l = pid >> 1;
        const int c_l  = ct_l * 32 + (l & 31);
        const int k_l  = kt_l * 16 + ((l >> 5) << 3);
        half8 h, lo;
#pragma unroll
        for (int j = 0; j < 8; ++j) {
            float v = S[k_l + j][c_l];
            _Float16 hv = (_Float16)v;
            h[j]  = hv;
            lo[j] = (_Float16)(v - (float)hv);
        }
        const int ct_g = (colbase >> 5) + ct_l;
        const int kt_g = (ktbase >> 4) + kt_l;
        const size_t off = (size_t)(ct_g * 16 + kt_g) * 64 + l;
        dhi[off] = *reinterpret_cast<uint4*>(&h);
        dlo[off] = *reinterpret_cast<uint4*>(&lo);
    }
}

// ---------------------------------------------------------------------------
// MFMA distance + per-row top-8, 32x32x16, TWO rowgroups per wave (64 rows):
// each LDS A-read feeds 6 MFMAs -> LDS pipe no longer the bottleneck.
// Block: 256 rows x span cols; 256 threads = 4 waves; 1 wave/SIMD (big RF).
// Grid: 16 rowtiles * nsplit. Wave w owns groups w and w+4 (32 rows each).
// D layout: col = lane&31 -> xi row; row r: xp col = (r&3)+8*(r>>2)+4*(l>>5).
// ---------------------------------------------------------------------------
__global__ __launch_bounds__(256, 1)
void dist_topk_mfma(const uint4* __restrict__ xpBhi, const uint4* __restrict__ xpBlo,
                    const uint4* __restrict__ xiBhi, const uint4* __restrict__ xiBlo,
                    const float* __restrict__ normP,
                    float* __restrict__ candV, int* __restrict__ candI,
                    int nsplit) {
    __shared__ __align__(16) char Abuf[2][32768];   // [buf][hi 16KB][lo 16KB]
    __shared__ __align__(16) float nPl[2048];       // 0.5 * normP

    const int t = threadIdx.x;
    const int w = t >> 6;
    const int l = t & 63;
    int rt, cs;
    if (nsplit == 16) { cs = ((blockIdx.x & 7) << 1) | ((blockIdx.x >> 3) & 1); rt = blockIdx.x >> 4; }
    else              { cs = blockIdx.x & 7;                                    rt = blockIdx.x >> 3; }
    const int niter = (MCOLS / 32) / nsplit;
    const int span  = MCOLS / nsplit;
    const int colbase = cs * span;
    const int ncand = nsplit * 8;

    for (int i = t; i < span; i += 256) nPl[i] = 0.5f * normP[colbase + i];

    // xi fragments: groups gA = w, gB = w+4 of the 8 groups in this 256-row tile
    uint4 bhA[16], blA[16], bhB[16], blB[16];
    const int ctgA = rt * 8 + w;
    const int ctgB = ctgA + 4;
#pragma unroll
    for (int kt = 0; kt < 16; ++kt) {
        bhA[kt] = xiBhi[(size_t)(ctgA * 16 + kt) * 64 + l];
        blA[kt] = xiBlo[(size_t)(ctgA * 16 + kt) * 64 + l];
        bhB[kt] = xiBhi[(size_t)(ctgB * 16 + kt) * 64 + l];
        blB[kt] = xiBlo[(size_t)(ctgB * 16 + kt) * 64 + l];
    }

    float bvA[8], bvB[8]; int biA[8], biB[8];
#pragma unroll
    for (int j = 0; j < 8; ++j) {
        bvA[j] = __uint_as_float((0x7f7ffff8u) | (unsigned)j);
        bvB[j] = bvA[j];
        biA[j] = -1; biB[j] = -1;
    }
    float worstA = bvA[7], tauA = bvA[7], gateA = bvA[7];
    float worstB = bvB[7], tauB = bvB[7], gateB = bvB[7];

    // staging: wave0 hi kt0-7, wave1 hi kt8-15, wave2 lo kt0-7, wave3 lo kt8-15
    const char* gb = (w >= 2) ? (const char*)xpBlo : (const char*)xpBhi;
    const char* srcBase = gb + (size_t)(cs * niter) * 16384 + (w & 1) * 8192 + l * 16;
    char* dbBase = &Abuf[0][(w >= 2 ? 16384 : 0) + (w & 1) * 8192];

    auto stage = [&](int it, int buf) {
        const char* src = srcBase + (size_t)it * 16384;
        char* db = dbBase + buf * 32768;
#pragma unroll
        for (int kt = 0; kt < 8; ++kt)
            __builtin_amdgcn_global_load_lds(
                (const __attribute__((address_space(1))) void*)(src + kt * 1024),
                (__attribute__((address_space(3))) void*)(db + kt * 1024),
                16, 0, 0);
    };

    stage(0, 0);
    asm volatile("s_waitcnt vmcnt(0)" ::: "memory");
    __builtin_amdgcn_s_barrier();

    for (int it = 0; it < niter; ++it) {
        if (it < niter - 1) {
            stage(it + 1, (it + 1) & 1);
            asm volatile("s_waitcnt vmcnt(8)" ::: "memory");
        } else {
            asm volatile("s_waitcnt vmcnt(0)" ::: "memory");
        }
        __builtin_amdgcn_s_barrier();
        __builtin_amdgcn_sched_barrier(0);

        const char* Ab = Abuf[it & 1];

        f32x16 a0A, a1A, a0B, a1B;
#pragma unroll
        for (int r = 0; r < 16; ++r) { a0A[r] = 0.0f; a1A[r] = 0.0f; a0B[r] = 0.0f; a1B[r] = 0.0f; }
        __builtin_amdgcn_s_setprio(1);
#pragma unroll
        for (int kt = 0; kt < 16; ++kt) {
            const half8 ah = *reinterpret_cast<const half8*>(Ab + kt * 1024 + l * 16);
            const half8 al = *reinterpret_cast<const half8*>(Ab + 16384 + kt * 1024 + l * 16);
            const half8 vhA = *reinterpret_cast<const half8*>(&bhA[kt]);
            const half8 vlA = *reinterpret_cast<const half8*>(&blA[kt]);
            const half8 vhB = *reinterpret_cast<const half8*>(&bhB[kt]);
            const half8 vlB = *reinterpret_cast<const half8*>(&blB[kt]);
            a0A = __builtin_amdgcn_mfma_f32_32x32x16_f16(ah, vhA, a0A, 0, 0, 0);
            a0B = __builtin_amdgcn_mfma_f32_32x32x16_f16(ah, vhB, a0B, 0, 0, 0);
            a1A = __builtin_amdgcn_mfma_f32_32x32x16_f16(ah, vlA, a1A, 0, 0, 0);
            a1B = __builtin_amdgcn_mfma_f32_32x32x16_f16(ah, vlB, a1B, 0, 0, 0);
            a0A = __builtin_amdgcn_mfma_f32_32x32x16_f16(al, vhA, a0A, 0, 0, 0);
            a0B = __builtin_amdgcn_mfma_f32_32x32x16_f16(al, vhB, a0B, 0, 0, 0);
        }
        __builtin_amdgcn_s_setprio(0);

        const int lq = (l >> 5) << 2;
        float dvA[16], dvB[16];
#pragma unroll
        for (int rq = 0; rq < 4; ++rq) {
            const float4 np4 = *reinterpret_cast<const float4*>(&nPl[it * 32 + rq * 8 + lq]);
            const float npv[4] = {np4.x, np4.y, np4.z, np4.w};
#pragma unroll
            for (int j = 0; j < 4; ++j) {
                const int r = rq * 4 + j;
                dvA[r] = npv[j] - (a0A[r] + a1A[r]);
                dvB[r] = npv[j] - (a0B[r] + a1B[r]);
            }
        }
        float mnA = dvA[0], mnB = dvB[0];
#pragma unroll
        for (int r = 1; r < 16; ++r) { mnA = fminf(mnA, dvA[r]); mnB = fminf(mnB, dvB[r]); }
        const int ib = colbase + it * 32 + lq;
        if (__any(mnA < gateA)) {
#pragma unroll
            for (int r = 0; r < 16; ++r) {
                const int cb = ib + (r & 3) + 8 * (r >> 2);
                TOPK_FAST(bvA, biA, worstA, gateA, tauA, dvA[r], cb);
            }
        }
        if (__any(mnB < gateB)) {
#pragma unroll
            for (int r = 0; r < 16; ++r) {
                const int cb = ib + (r & 3) + 8 * (r >> 2);
                TOPK_FAST(bvB, biB, worstB, gateB, tauB, dvB[r], cb);
            }
        }

        {
            tauA = fminf(worstA, __shfl_xor(worstA, 32));
            gateA = fminf(tauA, worstA);
            tauB = fminf(worstB, __shfl_xor(worstB, 32));
            gateB = fminf(tauB, worstB);
        }

        __builtin_amdgcn_s_barrier();
    }

    // merge scratch aliased onto Abuf: vals [0,16KB) A + [16,32KB)... layout:
    // A vals at f[0..2048), B vals at f[2048..4096), idx ints at f[4096..8192)
    float* mVal = (float*)&Abuf[0][0];
    int*   mIdx = (int*)&Abuf[0][16384];

    __syncthreads();
#pragma unroll
    for (int j = 0; j < 8; ++j) {
        mVal[t * 8 + j] = bvA[j];          mIdx[t * 8 + j] = biA[j];
        mVal[2048 + t * 8 + j] = bvB[j];   mIdx[2048 + t * 8 + j] = biB[j];
    }
    __syncthreads();
    {
        // t = local row 0..255: group g = t>>5, r32 = t&31
        const int g = t >> 5;
        const int r32 = t & 31;
        const int w_src = g & 3;
        const int off = (g >> 2) * 2048;
        const int t1 = w_src * 64 + r32;
        const int t2 = t1 + 32;
        float sv[8]; int si[8];
#pragma unroll
        for (int j = 0; j < 8; ++j) { sv[j] = 3.4e38f; si[j] = -1; }
        float wv = 3.4e38f; int wp = 0;
#pragma unroll
        for (int j = 0; j < 8; ++j) {
            const float v1 = mVal[off + t1 * 8 + j];
            TOPK_UPDATE(sv, si, wv, wp, v1, mIdx[off + t1 * 8 + j]);
            const float v2 = mVal[off + t2 * 8 + j];
            TOPK_UPDATE(sv, si, wv, wp, v2, mIdx[off + t2 * 8 + j]);
        }
        for (int a = 1; a < 8; ++a) {
            float v = sv[a]; int ii = si[a]; int b2 = a - 1;
            while (b2 >= 0 && sv[b2] > v) { sv[b2+1] = sv[b2]; si[b2+1] = si[b2]; --b2; }
            sv[b2+1] = v; si[b2+1] = ii;
        }
        const int row = rt * 256 + t;
#pragma unroll
        for (int j = 0; j < 8; ++j) {
            candV[row * ncand + cs * 8 + j] = sv[j];
            candI[row * ncand + cs * 8 + j] = si[j];
        }
    }
}

// ---------------------------------------------------------------------------
// MLP layer 1: CIN=256 (2x128 chunks), 64 outputs per block. Grid 640.
// ---------------------------------------------------------------------------
__global__ __launch_bounds__(256)
void gemm1_kernel(const float* __restrict__ Xp, const float* __restrict__ Xi,
                  const float* __restrict__ W, const float* __restrict__ bias,
                  float* __restrict__ outP, float* __restrict__ outI) {
    __shared__ __align__(16) float Wl[128][68];
    const int t = threadIdx.x;
    const bool isP = blockIdx.x < 512;
    const int bid  = isP ? blockIdx.x : blockIdx.x - 512;
    const float* X = isP ? Xp : Xi;
    const int rows = isP ? 16384 : 4096;
    float* outT = isP ? outP : outI;
    const int rowblk = bid >> 1;
    const int ch     = bid & 1;

    const int r   = rowblk * 64 + (t & 63);
    const int kgb = (t >> 6) * 16;

    float acc[16];
#pragma unroll
    for (int q = 0; q < 16; ++q) acc[q] = 0.0f;

    for (int half = 0; half < 2; ++half) {
        __syncthreads();
        for (int i = t; i < 128 * 64; i += 256) {
            int k = i >> 7, c = i & 127;
            Wl[c][k] = W[(ch * 64 + k) * 256 + half * 128 + c];
        }
        __syncthreads();
#pragma unroll 2
        for (int c = 0; c < 128; ++c) {
            const int cg = half * 128 + c;
            const float x = X[(r >> 12) * (CDIM * 4096) + cg * 4096 + (r & 4095)];
#pragma unroll
            for (int q = 0; q < 4; ++q) {
                const float4 wv = *reinterpret_cast<const float4*>(&Wl[c][kgb + 4 * q]);
                acc[4 * q + 0] = fmaf(x, wv.x, acc[4 * q + 0]);
                acc[4 * q + 1] = fmaf(x, wv.y, acc[4 * q + 1]);
                acc[4 * q + 2] = fmaf(x, wv.z, acc[4 * q + 2]);
                acc[4 * q + 3] = fmaf(x, wv.w, acc[4 * q + 3]);
            }
        }
    }
#pragma unroll
    for (int q = 0; q < 16; ++q) {
        const int k = ch * 64 + kgb + q;
        outT[k * rows + r] = acc[q] + bias[k];
    }
}

// ---------------------------------------------------------------------------
// MLP layer 2 (CIN=128, COUT=64, BN+ReLU on input). Grid 320.
// ---------------------------------------------------------------------------
__global__ __launch_bounds__(256)
void gemm2_kernel(const float* __restrict__ Hp, const float* __restrict__ Hi,
                  const float* __restrict__ W, const float* __restrict__ bias,
                  const float* __restrict__ statsP, const float* __restrict__ statsI,
                  const float* __restrict__ g, const float* __restrict__ be,
                  float* __restrict__ outP, float* __restrict__ outI) {
    __shared__ __align__(16) float Wl[128][68];
    __shared__ float scL[128], shL[128];
    const int t = threadIdx.x;
    const bool isP = blockIdx.x < 256;
    const float* X = isP ? Hp : Hi;
    const float* stats = isP ? statsP : statsI;
    const float invDenom = isP ? (1.0f / 16384.0f) : (1.0f / 4096.0f);
    const int rows = isP ? 16384 : 4096;
    const int blk  = isP ? blockIdx.x : blockIdx.x - 256;
    float* outT = isP ? outP : outI;

    for (int i = t; i < 128 * 64; i += 256) {
        int k = i >> 7, c = i & 127;
        Wl[c][k] = W[k * 128 + c];
    }
    if (t < 128) {
        float mean = stats[t] * invDenom;
        float var  = stats[128 + t] * invDenom - mean * mean;
        float sc   = rsqrtf(var + 1e-5f) * g[t];
        scL[t] = sc;
        shL[t] = be[t] - mean * sc;
    }
    __syncthreads();

    const int r   = blk * 64 + (t & 63);
    const int chb = (t >> 6) * 16;

    float acc[16];
#pragma unroll
    for (int q = 0; q < 16; ++q) acc[q] = 0.0f;

#pragma unroll 2
    for (int c = 0; c < 128; ++c) {
        float x = X[c * rows + r];
        x = fmaxf(fmaf(x, scL[c], shL[c]), 0.0f);
#pragma unroll
        for (int q = 0; q < 4; ++q) {
            const float4 wv = *reinterpret_cast<const float4*>(&Wl[c][chb + 4 * q]);
            acc[4 * q + 0] = fmaf(x, wv.x, acc[4 * q + 0]);
            acc[4 * q + 1] = fmaf(x, wv.y, acc[4 * q + 1]);
            acc[4 * q + 2] = fmaf(x, wv.z, acc[4 * q + 2]);
            acc[4 * q + 3] = fmaf(x, wv.w, acc[4 * q + 3]);
        }
    }
#pragma unroll
    for (int q = 0; q < 16; ++q) {
        const int k = chb + q;
        outT[k * rows + r] = acc[q] + bias[k];
    }
}

// ---------------------------------------------------------------------------
// Column stats for peers+input in one launch. Grid = 2*C.
// ---------------------------------------------------------------------------
__global__ __launch_bounds__(256)
void colstats2x_kernel(const float* __restrict__ Hp, const float* __restrict__ Hi,
                       int C, float* __restrict__ statsP, float* __restrict__ statsI) {
    __shared__ float rs[256], rq[256];
    const bool isP = blockIdx.x < (unsigned)C;
    const int c = isP ? blockIdx.x : blockIdx.x - C;
    const float* H = isP ? Hp : Hi;
    const int rows = isP ? 16384 : 4096;
    float* stats = isP ? statsP : statsI;
    const int t = threadIdx.x;
    float s = 0.0f, q = 0.0f;
    for (int r = t; r < rows; r += 256) {
        float v = H[c * rows + r];
        s += v;
        q = fmaf(v, v, q);
    }
    rs[t] = s; rq[t] = q;
    __syncthreads();
    for (int st = 128; st > 0; st >>= 1) {
        if (t < st) { rs[t] += rs[t + st]; rq[t] += rq[t + st]; }
        __syncthreads();
    }
    if (t == 0) { stats[c] = rs[0]; stats[C + c] = rq[0]; }
}

// ---------------------------------------------------------------------------
// a-scores for peers+input in one launch. Grid = 80.
// ---------------------------------------------------------------------------
__global__ __launch_bounds__(256)
void a2x_kernel(const float* __restrict__ Hp, const float* __restrict__ Hi,
                const float* __restrict__ statsP, const float* __restrict__ statsI,
                const float* __restrict__ g, const float* __restrict__ be,
                const float* __restrict__ cwP, const float* __restrict__ cbP,
                const float* __restrict__ cwI, const float* __restrict__ cbI,
                float* __restrict__ aP, float* __restrict__ aI) {
    __shared__ float scL[64], shL[64], cwL[64];
    const bool isP = blockIdx.x < 64;
    const float* H = isP ? Hp : Hi;
    const float* stats = isP ? statsP : statsI;
    const float* cw = isP ? cwP : cwI;
    const float* cb = isP ? cbP : cbI;
    float* aout = isP ? aP : aI;
    const int rows = isP ? 16384 : 4096;
    const float invDenom = isP ? (1.0f / 16384.0f) : (1.0f / 4096.0f);
    const int blk = isP ? blockIdx.x : blockIdx.x - 64;
    const int t = threadIdx.x;
    if (t < 64) {
        float mean = stats[t] * invDenom;
        float var  = stats[64 + t] * invDenom - mean * mean;
        float sc   = rsqrtf(var + 1e-5f) * g[t];
        scL[t] = sc;
        shL[t] = be[t] - mean * sc;
        cwL[t] = cw[t];
    }
    __syncthreads();
    const int row = blk * 256 + t;
    if (row < rows) {
        float a = 0.0f;
        for (int c = 0; c < 64; ++c) {
            float v = H[c * rows + row];
            a += fmaxf(fmaf(v, scL[c], shL[c]), 0.0f) * cwL[c];
        }
        aout[row] = a + cb[0];
    }
}

// ---------------------------------------------------------------------------
// Merge candidates -> per-row softmax weights + gather base addresses.
// ---------------------------------------------------------------------------
__global__ __launch_bounds__(256)
void merge_kernel(const float* __restrict__ candV, const int* __restrict__ candI,
                  const float* __restrict__ a1, const float* __restrict__ a2,
                  float* __restrict__ w8, int* __restrict__ gidx, int ncand) {
    const int row = blockIdx.x * 256 + threadIdx.x;
    float sv[8]; int si[8];
#pragma unroll
    for (int j = 0; j < 8; ++j) { sv[j] = 3.4e38f; si[j] = 0; }
    float w2 = 3.4e38f; int wp = 0;
    for (int k = 0; k < ncand; ++k) {
        const float v = candV[row * ncand + k];
        TOPK_UPDATE(sv, si, w2, wp, v, candI[row * ncand + k]);
    }
    for (int a = 1; a < 8; ++a) {
        float v = sv[a]; int ii = si[a]; int b = a - 1;
        while (b >= 0 && sv[b] > v) { sv[b + 1] = sv[b]; si[b + 1] = si[b]; --b; }
        sv[b + 1] = v; si[b + 1] = ii;
    }
    const float kth = sv[4];
    int cnt = 5;
    while (cnt < 8 && sv[cnt] <= kth) ++cnt;

    const float arow = a1[row];
    float s[8], e[8];
    float mx = -1e30f;
#pragma unroll
    for (int j = 0; j < 8; ++j) s[j] = 0.0f;
    for (int j = 0; j < cnt; ++j) {
        s[j] = softplusf(arow + a2[si[j]]);
        mx = fmaxf(mx, s[j]);
    }
    float Z = 0.0f;
    for (int j = 0; j < 8; ++j) {
        e[j] = (j < cnt) ? expf(s[j] - mx) : 0.0f;
        Z += e[j];
    }
#pragma unroll
    for (int j = 0; j < 8; ++j) {
        const int ix = (j < cnt) ? si[j] : si[0];
        w8[row * 8 + j]   = e[j] / Z;
        gidx[row * 8 + j] = (ix >> 12) * (CDIM * 4096) + (ix & 4095);
    }
}

// ---------------------------------------------------------------------------
// Gather: out[(256+c)*4096 + n] = sum_j w8[n][j] * PS[gidx[n][j] + c*4096].
// ---------------------------------------------------------------------------
__global__ __launch_bounds__(256)
void gather_kernel(const float* __restrict__ w8, const int* __restrict__ gidx,
                   const float* __restrict__ PS, float* __restrict__ dout) {
    const int t = threadIdx.x;
    const int rtile = blockIdx.x >> 4;
    const int chunk = blockIdx.x & 15;
    const int row = rtile * 64 + (t & 63);
    const int c0  = chunk * 16 + (t >> 6) * 4;

    float w[8]; int ab[8];
#pragma unroll
    for (int j = 0; j < 8; ++j) { w[j] = w8[row * 8 + j]; ab[j] = gidx[row * 8 + j]; }

#pragma unroll
    for (int cc = 0; cc < 4; ++cc) {
        const int c = c0 + cc;
        float acc = 0.0f;
#pragma unroll
        for (int j = 0; j < 8; ++j) acc += w[j] * PS[ab[j] + c * 4096];
        dout[(CDIM + c) * 4096 + row] = acc;
    }
}

// ---------------------------------------------------------------------------
extern "C" void kernel_launch(void* const* d_in, const int* in_sizes, int n_in,
                              void* d_out, int out_size, void* d_ws, size_t ws_size,
                              hipStream_t stream) {
    const float* inp_cont    = (const float*)d_in[0];
    const float* peers_cont  = (const float*)d_in[2];
    const float* peers_style = (const float*)d_in[3];
    const float* W1  = (const float*)d_in[4];
    const float* b1  = (const float*)d_in[5];
    const float* g1  = (const float*)d_in[6];
    const float* be1 = (const float*)d_in[7];
    const float* W2  = (const float*)d_in[8];
    const float* b2  = (const float*)d_in[9];
    const float* g2  = (const float*)d_in[10];
    const float* be2 = (const float*)d_in[11];
    const float* cw1 = (const float*)d_in[12];
    const float* cb1 = (const float*)d_in[13];
    const float* cw2 = (const float*)d_in[14];
    const float* cb2 = (const float*)d_in[15];
    float* out = (float*)d_out;
    char*  wsb = (char*)d_ws;

    int nsplit;
    if      (ws_size >= (size_t)25400000) nsplit = 16;
    else if (ws_size >= (size_t)23300000) nsplit = 8;
    else return;
    const int ncand = nsplit * 8;
    const size_t candBytes = (size_t)NROWS * ncand * 4;

    // workspace layout (bytes)
    uint4* xpBhi = (uint4*)(wsb + 0);                    //  8 MB
    uint4* xpBlo = (uint4*)(wsb + 8388608);              //  8 MB
    uint4* xiBhi = (uint4*)(wsb + 16777216);             //  2 MB
    uint4* xiBlo = (uint4*)(wsb + 18874368);             //  2 MB
    float* normP = (float*)(wsb + 20971520);             //  64 KB
    float* normI = (float*)(wsb + 21037056);             //  16 KB
    float* candV = (float*)(wsb + 21053440);             //  candBytes
    int*   candI = (int*)  (wsb + 21053440 + candBytes); //  candBytes
    char*  tail  = wsb + 21053440 + 2 * candBytes;
    float* a2    = (float*)(tail);                       //  64 KB
    float* a1    = (float*)(tail + 65536);               //  16 KB
    float* s1p   = (float*)(tail + 81920);               //  1 KB
    float* s1i   = (float*)(tail + 82944);               //  1 KB
    float* s2p   = (float*)(tail + 83968);               //  512
    float* s2i   = (float*)(tail + 84480);               //  512
    // Aliased AFTER dist kernel completes:
    float* H1Tp  = (float*)(wsb + 0);                    // 8 MB
    float* H2Tp  = (float*)(wsb + 8388608);              // 4 MB
    float* H1Ti  = (float*)(wsb + 16777216);             // 2 MB
    float* H2Ti  = (float*)(wsb + 18874368);             // 1 MB (ends 19922944)
    float* w8    = (float*)(wsb + 19922944);             // 128 KB
    int*   gidx  = (int*)  (wsb + 20054016);             // 128 KB

    copy_kernel<<<1024, 256, 0, stream>>>((const float4*)inp_cont, (float4*)out, 262144);
    norms_kernel<<<320, 256, 0, stream>>>(inp_cont, peers_cont, normI, normP);
    convert_kernel<<<256, 256, 0, stream>>>(inp_cont, xiBhi, xiBlo, 4096);
    convert_kernel<<<1024, 256, 0, stream>>>(peers_cont, xpBhi, xpBlo, 16384);

    dist_topk_mfma<<<16 * nsplit, 256, 0, stream>>>(xpBhi, xpBlo, xiBhi, xiBlo,
                                                    normP, candV, candI, nsplit);

    gemm1_kernel<<<640, 256, 0, stream>>>(peers_cont, inp_cont, W1, b1, H1Tp, H1Ti);
    colstats2x_kernel<<<256, 256, 0, stream>>>(H1Tp, H1Ti, 128, s1p, s1i);
    gemm2_kernel<<<320, 256, 0, stream>>>(H1Tp, H1Ti, W2, b2, s1p, s1i, g1, be1, H2Tp, H2Ti);
    colstats2x_kernel<<<128, 256, 0, stream>>>(H2Tp, H2Ti, 64, s2p, s2i);
    a2x_kernel<<<80, 256, 0, stream>>>(H2Tp, H2Ti, s2p, s2i, g2, be2,
                                       cw2, cb2, cw1, cb1, a2, a1);

    merge_kernel<<<16, 256, 0, stream>>>(candV, candI, a1, a2, w8, gidx, ncand);
    gather_kernel<<<1024, 256, 0, stream>>>(w8, gidx, peers_style, out);
}

// Round 17
// 340.047 us; speedup vs baseline: 1.1435x; 1.1435x over previous
//
#include <hip/hip_runtime.h>
#include <math.h>

#define NROWS 4096
#define MCOLS 16384
#define CDIM  256

typedef _Float16 half8 __attribute__((ext_vector_type(8)));
typedef float f32x4 __attribute__((ext_vector_type(4)));
typedef float f32x16 __attribute__((ext_vector_type(16)));

static __device__ __forceinline__ float softplusf(float x) {
    return fmaxf(x, 0.0f) + log1pf(expf(-fabsf(x)));
}

// Classic top-8 update (merge phases only)
#define TOPK_UPDATE(BV, BI, WORST, WP, V, IDX)                                 \
    if ((V) < (WORST)) {                                                       \
        BV[WP] = (V); BI[WP] = (IDX);                                          \
        WORST = BV[0]; WP = 0;                                                 \
        _Pragma("unroll")                                                      \
        for (int _q = 1; _q < 8; ++_q)                                         \
            if (BV[_q] > WORST) { WORST = BV[_q]; WP = _q; }                   \
    }

// Hot-loop top-8: slot index in 3 LSBs; worst via max-tree; gate = min(tau, worst).
#define TOPK_FAST(BV, BI, WORST, GATE, TAU, V, IDX)                            \
    if ((V) < (GATE)) {                                                        \
        const int _wp = __float_as_int(WORST) & 7;                             \
        BV[_wp] = __uint_as_float((__float_as_uint(V) & ~7u) | (unsigned)_wp); \
        BI[_wp] = (IDX);                                                       \
        const float _m0 = fmaxf(fmaxf(BV[0], BV[1]), fmaxf(BV[2], BV[3]));     \
        const float _m1 = fmaxf(fmaxf(BV[4], BV[5]), fmaxf(BV[6], BV[7]));     \
        WORST = fmaxf(_m0, _m1);                                               \
        GATE = fminf(TAU, WORST);                                              \
    }

// ---------------------------------------------------------------------------
// Passthrough copy
// ---------------------------------------------------------------------------
__global__ __launch_bounds__(256)
void copy_kernel(const float4* __restrict__ src, float4* __restrict__ dst, int n4) {
    int i = blockIdx.x * blockDim.x + threadIdx.x;
    if (i < n4) dst[i] = src[i];
}

// ---------------------------------------------------------------------------
// Column norms, fp32 tree (4 threads/column x 64 channels + shfl combine).
// ---------------------------------------------------------------------------
__global__ __launch_bounds__(256)
void norms_kernel(const float* __restrict__ xiT, const float* __restrict__ xpT,
                  float* __restrict__ normI, float* __restrict__ normP) {
    const int t = threadIdx.x;
    const int col = blockIdx.x * 64 + (t >> 2);
    const int sub = t & 3;
    const float* p;
    int base;
    if (col < MCOLS) { p = xpT; base = (col >> 12) * (CDIM * 4096) + (col & 4095); }
    else             { p = xiT; base = col - MCOLS; }
    float s = 0.0f;
#pragma unroll 8
    for (int k = 0; k < 64; ++k) {
        const float v = p[base + (sub * 64 + k) * 4096];
        s = fmaf(v, v, s);
    }
    s += __shfl_xor(s, 1);
    s += __shfl_xor(s, 2);
    if (sub == 0) {
        if (col < MCOLS) normP[col] = s;
        else             normI[col - MCOLS] = s;
    }
}

// ---------------------------------------------------------------------------
// fp32 [K=256][cols] -> fragment-ready fp16 hi/lo for 32x32x16 MFMA.
// Chunk (ct32*16 + kt)*64 + lane holds 8 halves:
//   element = x[col = ct32*32 + (lane&31)][k = kt*16 + (lane>>5)*8 + j]
// ---------------------------------------------------------------------------
__global__ __launch_bounds__(256)
void convert_kernel(const float* __restrict__ src, uint4* __restrict__ dhi,
                    uint4* __restrict__ dlo, int ncols) {
    __shared__ float S[64][65];
    const int t = threadIdx.x;
    const int tilesPerRow = ncols >> 6;
    const int colbase = (blockIdx.x % tilesPerRow) << 6;
    const int ktbase  = (blockIdx.x / tilesPerRow) << 6;
    const int b = colbase >> 12;
    const int pixbase = colbase & 4095;
    const float* sp = src + (size_t)b * (CDIM * 4096) + (size_t)ktbase * 4096 + pixbase;

    for (int i = t; i < 4096; i += 256) {
        int kk = i >> 6, cc = i & 63;
        S[kk][cc] = sp[kk * 4096 + cc];
    }
    __syncthreads();

    const int l = t & 63;
#pragma unroll
    for (int s = 0; s < 2; ++s) {
        const int pid  = (t >> 6) + 4 * s;   // 0..7
        const int ct_l = pid & 1;
        const int kt_l = pid >> 1;
        const int c_l  = ct_l * 32 + (l & 31);
        const int k_l  = kt_l * 16 + ((l >> 5) << 3);
        half8 h, lo;
#pragma unroll
        for (int j = 0; j < 8; ++j) {
            float v = S[k_l + j][c_l];
            _Float16 hv = (_Float16)v;
            h[j]  = hv;
            lo[j] = (_Float16)(v - (float)hv);
        }
        const int ct_g = (colbase >> 5) + ct_l;
        const int kt_g = (ktbase >> 4) + kt_l;
        const size_t off = (size_t)(ct_g * 16 + kt_g) * 64 + l;
        dhi[off] = *reinterpret_cast<uint4*>(&h);
        dlo[off] = *reinterpret_cast<uint4*>(&lo);
    }
}

// ---------------------------------------------------------------------------
// MFMA distance + per-row top-8 using 32x32x16 (R15 optimum config).
// Grid: 32 rowtiles (128 rows) * nsplit; 256 threads = 4 waves, 2 waves/SIMD.
// Wave w owns xi group ctg = rt*4+w (32 rows). Per iter: 32 xp cols.
// D layout: col = lane&31 -> xi row; row r: xp col = (r&3)+8*(r>>2)+4*(l>>5).
// Counted-vmcnt pipeline; v = 0.5*normP - dot domain; XCD cs map.
// ---------------------------------------------------------------------------
__global__ __launch_bounds__(256, 2)
void dist_topk_mfma(const uint4* __restrict__ xpBhi, const uint4* __restrict__ xpBlo,
                    const uint4* __restrict__ xiBhi, const uint4* __restrict__ xiBlo,
                    const float* __restrict__ normP,
                    float* __restrict__ candV, int* __restrict__ candI,
                    int nsplit) {
    __shared__ __align__(16) char Abuf[2][32768];   // [buf][hi 16KB][lo 16KB]
    __shared__ __align__(16) float nPl[2048];       // 0.5 * normP

    const int t = threadIdx.x;
    const int w = t >> 6;
    const int l = t & 63;
    int rt, cs;
    if (nsplit == 16) { cs = ((blockIdx.x & 7) << 1) | ((blockIdx.x >> 3) & 1); rt = blockIdx.x >> 4; }
    else              { cs = blockIdx.x & 7;                                    rt = blockIdx.x >> 3; }
    const int niter = (MCOLS / 32) / nsplit;
    const int span  = MCOLS / nsplit;
    const int colbase = cs * span;
    const int ncand = nsplit * 8;

    for (int i = t; i < span; i += 256) nPl[i] = 0.5f * normP[colbase + i];

    // xi fragments: group ctg = rt*4 + w covers rows rt*128 + w*32 .. +32
    uint4 bh[16], bl[16];
    const int ctg = rt * 4 + w;
#pragma unroll
    for (int kt = 0; kt < 16; ++kt) {
        bh[kt] = xiBhi[(size_t)(ctg * 16 + kt) * 64 + l];
        bl[kt] = xiBlo[(size_t)(ctg * 16 + kt) * 64 + l];
    }

    float bv[8]; int bi[8];
#pragma unroll
    for (int j = 0; j < 8; ++j) {
        bv[j] = __uint_as_float((0x7f7ffff8u) | (unsigned)j);
        bi[j] = -1;
    }
    float worst = bv[7], tau = bv[7], gate = bv[7];

    // staging: wave0 hi kt0-7, wave1 hi kt8-15, wave2 lo kt0-7, wave3 lo kt8-15
    const char* gb = (w >= 2) ? (const char*)xpBlo : (const char*)xpBhi;
    const char* srcBase = gb + (size_t)(cs * niter) * 16384 + (w & 1) * 8192 + l * 16;
    char* dbBase = &Abuf[0][(w >= 2 ? 16384 : 0) + (w & 1) * 8192];

    auto stage = [&](int it, int buf) {
        const char* src = srcBase + (size_t)it * 16384;
        char* db = dbBase + buf * 32768;
#pragma unroll
        for (int kt = 0; kt < 8; ++kt)
            __builtin_amdgcn_global_load_lds(
                (const __attribute__((address_space(1))) void*)(src + kt * 1024),
                (__attribute__((address_space(3))) void*)(db + kt * 1024),
                16, 0, 0);
    };

    stage(0, 0);
    asm volatile("s_waitcnt vmcnt(0)" ::: "memory");
    __builtin_amdgcn_s_barrier();

    for (int it = 0; it < niter; ++it) {
        if (it < niter - 1) {
            stage(it + 1, (it + 1) & 1);
            asm volatile("s_waitcnt vmcnt(8)" ::: "memory");
        } else {
            asm volatile("s_waitcnt vmcnt(0)" ::: "memory");
        }
        __builtin_amdgcn_s_barrier();
        __builtin_amdgcn_sched_barrier(0);

        const char* Ab = Abuf[it & 1];

        f32x16 a0, a1;
#pragma unroll
        for (int r = 0; r < 16; ++r) { a0[r] = 0.0f; a1[r] = 0.0f; }
        __builtin_amdgcn_s_setprio(1);
#pragma unroll
        for (int kt = 0; kt < 16; ++kt) {
            const half8 ah = *reinterpret_cast<const half8*>(Ab + kt * 1024 + l * 16);
            const half8 al = *reinterpret_cast<const half8*>(Ab + 16384 + kt * 1024 + l * 16);
            const half8 vh = *reinterpret_cast<const half8*>(&bh[kt]);
            const half8 vl = *reinterpret_cast<const half8*>(&bl[kt]);
            a0 = __builtin_amdgcn_mfma_f32_32x32x16_f16(ah, vh, a0, 0, 0, 0);
            a1 = __builtin_amdgcn_mfma_f32_32x32x16_f16(ah, vl, a1, 0, 0, 0);
            a0 = __builtin_amdgcn_mfma_f32_32x32x16_f16(al, vh, a0, 0, 0, 0);
        }
        __builtin_amdgcn_s_setprio(0);

        // dv[r]: xp col = it*32 + (r&3) + 8*(r>>2) + 4*(l>>5)
        float dv[16];
        const int lq = (l >> 5) << 2;
#pragma unroll
        for (int rq = 0; rq < 4; ++rq) {
            const float4 np4 = *reinterpret_cast<const float4*>(&nPl[it * 32 + rq * 8 + lq]);
            const float npv[4] = {np4.x, np4.y, np4.z, np4.w};
#pragma unroll
            for (int j = 0; j < 4; ++j) {
                const int r = rq * 4 + j;
                dv[r] = npv[j] - (a0[r] + a1[r]);
            }
        }
        float mn = dv[0];
#pragma unroll
        for (int r = 1; r < 16; ++r) mn = fminf(mn, dv[r]);
        const int ib = colbase + it * 32 + lq;
        if (__any(mn < gate)) {
#pragma unroll
            for (int r = 0; r < 16; ++r) {
                const int cb = ib + (r & 3) + 8 * (r >> 2);
                TOPK_FAST(bv, bi, worst, gate, tau, dv[r], cb);
            }
        }

        {
            tau = fminf(worst, __shfl_xor(worst, 32));
            gate = fminf(tau, worst);
        }

        __builtin_amdgcn_s_barrier();
    }

    // merge scratch aliased onto Abuf
    float* mVal = (float*)&Abuf[0][0];
    int*   mIdx = (int*)&Abuf[0][8192];

    __syncthreads();
#pragma unroll
    for (int j = 0; j < 8; ++j) { mVal[t * 8 + j] = bv[j]; mIdx[t * 8 + j] = bi[j]; }
    __syncthreads();
    if (t < 128) {
        // row_local = t: wave w_r = t>>5, xi row r32 = t&31; lanes w_r*64+r32 and +32
        const int t1 = ((t >> 5) << 6) + (t & 31);
        const int t2 = t1 + 32;
        float sv[8]; int si[8];
#pragma unroll
        for (int j = 0; j < 8; ++j) { sv[j] = 3.4e38f; si[j] = -1; }
        float wv = 3.4e38f; int wp = 0;
#pragma unroll
        for (int j = 0; j < 8; ++j) {
            const float v1 = mVal[t1 * 8 + j];
            TOPK_UPDATE(sv, si, wv, wp, v1, mIdx[t1 * 8 + j]);
            const float v2 = mVal[t2 * 8 + j];
            TOPK_UPDATE(sv, si, wv, wp, v2, mIdx[t2 * 8 + j]);
        }
        for (int a = 1; a < 8; ++a) {
            float v = sv[a]; int ii = si[a]; int b2 = a - 1;
            while (b2 >= 0 && sv[b2] > v) { sv[b2+1] = sv[b2]; si[b2+1] = si[b2]; --b2; }
            sv[b2+1] = v; si[b2+1] = ii;
        }
        const int row = rt * 128 + t;
#pragma unroll
        for (int j = 0; j < 8; ++j) {
            candV[row * ncand + cs * 8 + j] = sv[j];
            candI[row * ncand + cs * 8 + j] = si[j];
        }
    }
}

// ---------------------------------------------------------------------------
// MLP layer 1: CIN=256 (2x128 chunks), 64 outputs per block. Grid 640.
// ---------------------------------------------------------------------------
__global__ __launch_bounds__(256)
void gemm1_kernel(const float* __restrict__ Xp, const float* __restrict__ Xi,
                  const float* __restrict__ W, const float* __restrict__ bias,
                  float* __restrict__ outP, float* __restrict__ outI) {
    __shared__ __align__(16) float Wl[128][68];
    const int t = threadIdx.x;
    const bool isP = blockIdx.x < 512;
    const int bid  = isP ? blockIdx.x : blockIdx.x - 512;
    const float* X = isP ? Xp : Xi;
    const int rows = isP ? 16384 : 4096;
    float* outT = isP ? outP : outI;
    const int rowblk = bid >> 1;
    const int ch     = bid & 1;

    const int r   = rowblk * 64 + (t & 63);
    const int kgb = (t >> 6) * 16;

    float acc[16];
#pragma unroll
    for (int q = 0; q < 16; ++q) acc[q] = 0.0f;

    for (int half = 0; half < 2; ++half) {
        __syncthreads();
        for (int i = t; i < 128 * 64; i += 256) {
            int k = i >> 7, c = i & 127;
            Wl[c][k] = W[(ch * 64 + k) * 256 + half * 128 + c];
        }
        __syncthreads();
#pragma unroll 2
        for (int c = 0; c < 128; ++c) {
            const int cg = half * 128 + c;
            const float x = X[(r >> 12) * (CDIM * 4096) + cg * 4096 + (r & 4095)];
#pragma unroll
            for (int q = 0; q < 4; ++q) {
                const float4 wv = *reinterpret_cast<const float4*>(&Wl[c][kgb + 4 * q]);
                acc[4 * q + 0] = fmaf(x, wv.x, acc[4 * q + 0]);
                acc[4 * q + 1] = fmaf(x, wv.y, acc[4 * q + 1]);
                acc[4 * q + 2] = fmaf(x, wv.z, acc[4 * q + 2]);
                acc[4 * q + 3] = fmaf(x, wv.w, acc[4 * q + 3]);
            }
        }
    }
#pragma unroll
    for (int q = 0; q < 16; ++q) {
        const int k = ch * 64 + kgb + q;
        outT[k * rows + r] = acc[q] + bias[k];
    }
}

// ---------------------------------------------------------------------------
// MLP layer 2 (CIN=128, COUT=64, BN+ReLU on input). Grid 320.
// ---------------------------------------------------------------------------
__global__ __launch_bounds__(256)
void gemm2_kernel(const float* __restrict__ Hp, const float* __restrict__ Hi,
                  const float* __restrict__ W, const float* __restrict__ bias,
                  const float* __restrict__ statsP, const float* __restrict__ statsI,
                  const float* __restrict__ g, const float* __restrict__ be,
                  float* __restrict__ outP, float* __restrict__ outI) {
    __shared__ __align__(16) float Wl[128][68];
    __shared__ float scL[128], shL[128];
    const int t = threadIdx.x;
    const bool isP = blockIdx.x < 256;
    const float* X = isP ? Hp : Hi;
    const float* stats = isP ? statsP : statsI;
    const float invDenom = isP ? (1.0f / 16384.0f) : (1.0f / 4096.0f);
    const int rows = isP ? 16384 : 4096;
    const int blk  = isP ? blockIdx.x : blockIdx.x - 256;
    float* outT = isP ? outP : outI;

    for (int i = t; i < 128 * 64; i += 256) {
        int k = i >> 7, c = i & 127;
        Wl[c][k] = W[k * 128 + c];
    }
    if (t < 128) {
        float mean = stats[t] * invDenom;
        float var  = stats[128 + t] * invDenom - mean * mean;
        float sc   = rsqrtf(var + 1e-5f) * g[t];
        scL[t] = sc;
        shL[t] = be[t] - mean * sc;
    }
    __syncthreads();

    const int r   = blk * 64 + (t & 63);
    const int chb = (t >> 6) * 16;

    float acc[16];
#pragma unroll
    for (int q = 0; q < 16; ++q) acc[q] = 0.0f;

#pragma unroll 2
    for (int c = 0; c < 128; ++c) {
        float x = X[c * rows + r];
        x = fmaxf(fmaf(x, scL[c], shL[c]), 0.0f);
#pragma unroll
        for (int q = 0; q < 4; ++q) {
            const float4 wv = *reinterpret_cast<const float4*>(&Wl[c][chb + 4 * q]);
            acc[4 * q + 0] = fmaf(x, wv.x, acc[4 * q + 0]);
            acc[4 * q + 1] = fmaf(x, wv.y, acc[4 * q + 1]);
            acc[4 * q + 2] = fmaf(x, wv.z, acc[4 * q + 2]);
            acc[4 * q + 3] = fmaf(x, wv.w, acc[4 * q + 3]);
        }
    }
#pragma unroll
    for (int q = 0; q < 16; ++q) {
        const int k = chb + q;
        outT[k * rows + r] = acc[q] + bias[k];
    }
}

// ---------------------------------------------------------------------------
// Column stats for peers+input in one launch. Grid = 2*C.
// ---------------------------------------------------------------------------
__global__ __launch_bounds__(256)
void colstats2x_kernel(const float* __restrict__ Hp, const float* __restrict__ Hi,
                       int C, float* __restrict__ statsP, float* __restrict__ statsI) {
    __shared__ float rs[256], rq[256];
    const bool isP = blockIdx.x < (unsigned)C;
    const int c = isP ? blockIdx.x : blockIdx.x - C;
    const float* H = isP ? Hp : Hi;
    const int rows = isP ? 16384 : 4096;
    float* stats = isP ? statsP : statsI;
    const int t = threadIdx.x;
    float s = 0.0f, q = 0.0f;
    for (int r = t; r < rows; r += 256) {
        float v = H[c * rows + r];
        s += v;
        q = fmaf(v, v, q);
    }
    rs[t] = s; rq[t] = q;
    __syncthreads();
    for (int st = 128; st > 0; st >>= 1) {
        if (t < st) { rs[t] += rs[t + st]; rq[t] += rq[t + st]; }
        __syncthreads();
    }
    if (t == 0) { stats[c] = rs[0]; stats[C + c] = rq[0]; }
}

// ---------------------------------------------------------------------------
// a-scores for peers+input in one launch. Grid = 80.
// ---------------------------------------------------------------------------
__global__ __launch_bounds__(256)
void a2x_kernel(const float* __restrict__ Hp, const float* __restrict__ Hi,
                const float* __restrict__ statsP, const float* __restrict__ statsI,
                const float* __restrict__ g, const float* __restrict__ be,
                const float* __restrict__ cwP, const float* __restrict__ cbP,
                const float* __restrict__ cwI, const float* __restrict__ cbI,
                float* __restrict__ aP, float* __restrict__ aI) {
    __shared__ float scL[64], shL[64], cwL[64];
    const bool isP = blockIdx.x < 64;
    const float* H = isP ? Hp : Hi;
    const float* stats = isP ? statsP : statsI;
    const float* cw = isP ? cwP : cwI;
    const float* cb = isP ? cbP : cbI;
    float* aout = isP ? aP : aI;
    const int rows = isP ? 16384 : 4096;
    const float invDenom = isP ? (1.0f / 16384.0f) : (1.0f / 4096.0f);
    const int blk = isP ? blockIdx.x : blockIdx.x - 64;
    const int t = threadIdx.x;
    if (t < 64) {
        float mean = stats[t] * invDenom;
        float var  = stats[64 + t] * invDenom - mean * mean;
        float sc   = rsqrtf(var + 1e-5f) * g[t];
        scL[t] = sc;
        shL[t] = be[t] - mean * sc;
        cwL[t] = cw[t];
    }
    __syncthreads();
    const int row = blk * 256 + t;
    if (row < rows) {
        float a = 0.0f;
        for (int c = 0; c < 64; ++c) {
            float v = H[c * rows + row];
            a += fmaxf(fmaf(v, scL[c], shL[c]), 0.0f) * cwL[c];
        }
        aout[row] = a + cb[0];
    }
}

// ---------------------------------------------------------------------------
// Transpose peers_style [4][256][4096] -> PS_T[m = b*4096+pix][256].
// 64ch x 64pix tiles; grid 1024 = 4 b x 4 cgroup x 64 pixgroup.
// ---------------------------------------------------------------------------
__global__ __launch_bounds__(256)
void transpose_ps_kernel(const float* __restrict__ PS, float* __restrict__ PST) {
    __shared__ float S[64][65];
    const int t = threadIdx.x;
    const int bid = blockIdx.x;
    const int b  = bid >> 8;
    const int cg = (bid >> 6) & 3;
    const int pg = bid & 63;
    const float* src = PS + (size_t)b * (CDIM * 4096) + (size_t)(cg * 64) * 4096 + pg * 64;
    for (int i = t; i < 4096; i += 256) {
        const int ch = i >> 6, px = i & 63;
        S[ch][px] = src[ch * 4096 + px];
    }
    __syncthreads();
    float* dst = PST + ((size_t)b * 4096 + pg * 64) * CDIM + cg * 64;
    for (int i = t; i < 4096; i += 256) {
        const int px = i >> 6, ch = i & 63;
        dst[(size_t)px * CDIM + ch] = S[ch][px];
    }
}

// ---------------------------------------------------------------------------
// Merge candidates -> per-row softmax weights + plain neighbor indices.
// ---------------------------------------------------------------------------
__global__ __launch_bounds__(256)
void merge_kernel(const float* __restrict__ candV, const int* __restrict__ candI,
                  const float* __restrict__ a1, const float* __restrict__ a2,
                  float* __restrict__ w8, int* __restrict__ gidx, int ncand) {
    const int row = blockIdx.x * 256 + threadIdx.x;
    float sv[8]; int si[8];
#pragma unroll
    for (int j = 0; j < 8; ++j) { sv[j] = 3.4e38f; si[j] = 0; }
    float w2 = 3.4e38f; int wp = 0;
    for (int k = 0; k < ncand; ++k) {
        const float v = candV[row * ncand + k];
        TOPK_UPDATE(sv, si, w2, wp, v, candI[row * ncand + k]);
    }
    for (int a = 1; a < 8; ++a) {
        float v = sv[a]; int ii = si[a]; int b = a - 1;
        while (b >= 0 && sv[b] > v) { sv[b + 1] = sv[b]; si[b + 1] = si[b]; --b; }
        sv[b + 1] = v; si[b + 1] = ii;
    }
    const float kth = sv[4];
    int cnt = 5;
    while (cnt < 8 && sv[cnt] <= kth) ++cnt;

    const float arow = a1[row];
    float s[8], e[8];
    float mx = -1e30f;
#pragma unroll
    for (int j = 0; j < 8; ++j) s[j] = 0.0f;
    for (int j = 0; j < cnt; ++j) {
        s[j] = softplusf(arow + a2[si[j]]);
        mx = fmaxf(mx, s[j]);
    }
    float Z = 0.0f;
    for (int j = 0; j < 8; ++j) {
        e[j] = (j < cnt) ? expf(s[j] - mx) : 0.0f;
        Z += e[j];
    }
#pragma unroll
    for (int j = 0; j < 8; ++j) {
        w8[row * 8 + j]   = e[j] / Z;
        gidx[row * 8 + j] = (j < cnt) ? si[j] : si[0];
    }
}

// ---------------------------------------------------------------------------
// Gather from transposed style: coalesced 1KB reads per neighbor.
// Grid 128 (32 rows each); wave w handles rows w*8..w*8+7; lane = 4 channels.
// LDS transpose tile -> semi-coalesced dout writes.
// ---------------------------------------------------------------------------
__global__ __launch_bounds__(256)
void gather_kernel(const float* __restrict__ w8, const int* __restrict__ gidx,
                   const float* __restrict__ PST, float* __restrict__ dout) {
    __shared__ float T[32][261];
    const int t = threadIdx.x;
    const int w = t >> 6;
    const int l = t & 63;
    const int rowbase = blockIdx.x * 32;

#pragma unroll
    for (int rr = 0; rr < 8; ++rr) {
        const int rloc = w * 8 + rr;
        const int row = rowbase + rloc;
        float ax = 0.0f, ay = 0.0f, az = 0.0f, aw = 0.0f;
#pragma unroll
        for (int j = 0; j < 8; ++j) {
            const float wj = w8[row * 8 + j];
            const int m = gidx[row * 8 + j];
            const float4 v = *reinterpret_cast<const float4*>(&PST[(size_t)m * CDIM + l * 4]);
            ax = fmaf(wj, v.x, ax);
            ay = fmaf(wj, v.y, ay);
            az = fmaf(wj, v.z, az);
            aw = fmaf(wj, v.w, aw);
        }
        T[rloc][l * 4 + 0] = ax;
        T[rloc][l * 4 + 1] = ay;
        T[rloc][l * 4 + 2] = az;
        T[rloc][l * 4 + 3] = aw;
    }
    __syncthreads();

    const int rl = t & 31;
    const int cb = t >> 5;     // 0..7
#pragma unroll
    for (int k = 0; k < 32; ++k) {
        const int c = cb + 8 * k;
        dout[(size_t)(CDIM + c) * 4096 + rowbase + rl] = T[rl][c];
    }
}

// ---------------------------------------------------------------------------
extern "C" void kernel_launch(void* const* d_in, const int* in_sizes, int n_in,
                              void* d_out, int out_size, void* d_ws, size_t ws_size,
                              hipStream_t stream) {
    const float* inp_cont    = (const float*)d_in[0];
    const float* peers_cont  = (const float*)d_in[2];
    const float* peers_style = (const float*)d_in[3];
    const float* W1  = (const float*)d_in[4];
    const float* b1  = (const float*)d_in[5];
    const float* g1  = (const float*)d_in[6];
    const float* be1 = (const float*)d_in[7];
    const float* W2  = (const float*)d_in[8];
    const float* b2  = (const float*)d_in[9];
    const float* g2  = (const float*)d_in[10];
    const float* be2 = (const float*)d_in[11];
    const float* cw1 = (const float*)d_in[12];
    const float* cb1 = (const float*)d_in[13];
    const float* cw2 = (const float*)d_in[14];
    const float* cb2 = (const float*)d_in[15];
    float* out = (float*)d_out;
    char*  wsb = (char*)d_ws;

    int nsplit;
    if      (ws_size >= (size_t)25400000) nsplit = 16;
    else if (ws_size >= (size_t)23300000) nsplit = 8;
    else return;
    const int ncand = nsplit * 8;
    const size_t candBytes = (size_t)NROWS * ncand * 4;

    // workspace layout (bytes)
    uint4* xpBhi = (uint4*)(wsb + 0);                    //  8 MB
    uint4* xpBlo = (uint4*)(wsb + 8388608);              //  8 MB
    uint4* xiBhi = (uint4*)(wsb + 16777216);             //  2 MB
    uint4* xiBlo = (uint4*)(wsb + 18874368);             //  2 MB
    float* normP = (float*)(wsb + 20971520);             //  64 KB
    float* normI = (float*)(wsb + 21037056);             //  16 KB
    float* candV = (float*)(wsb + 21053440);             //  candBytes
    int*   candI = (int*)  (wsb + 21053440 + candBytes); //  candBytes
    char*  tail  = wsb + 21053440 + 2 * candBytes;
    float* a2    = (float*)(tail);                       //  64 KB
    float* a1    = (float*)(tail + 65536);               //  16 KB
    float* s1p   = (float*)(tail + 81920);               //  1 KB
    float* s1i   = (float*)(tail + 82944);               //  1 KB
    float* s2p   = (float*)(tail + 83968);               //  512
    float* s2i   = (float*)(tail + 84480);               //  512
    // Aliased AFTER dist kernel completes:
    float* H1Tp  = (float*)(wsb + 0);                    // 8 MB
    float* H2Tp  = (float*)(wsb + 8388608);              // 4 MB
    float* H1Ti  = (float*)(wsb + 16777216);             // 2 MB
    float* H2Ti  = (float*)(wsb + 18874368);             // 1 MB (ends 19922944)
    float* w8    = (float*)(wsb + 19922944);             // 128 KB
    int*   gidx  = (int*)  (wsb + 20054016);             // 128 KB
    // Aliased AFTER a2x completes (H buffers dead): PS_T 16 MB at offset 0
    float* PST   = (float*)(wsb + 0);

    copy_kernel<<<1024, 256, 0, stream>>>((const float4*)inp_cont, (float4*)out, 262144);
    norms_kernel<<<320, 256, 0, stream>>>(inp_cont, peers_cont, normI, normP);
    convert_kernel<<<256, 256, 0, stream>>>(inp_cont, xiBhi, xiBlo, 4096);
    convert_kernel<<<1024, 256, 0, stream>>>(peers_cont, xpBhi, xpBlo, 16384);

    dist_topk_mfma<<<32 * nsplit, 256, 0, stream>>>(xpBhi, xpBlo, xiBhi, xiBlo,
                                                    normP, candV, candI, nsplit);

    gemm1_kernel<<<640, 256, 0, stream>>>(peers_cont, inp_cont, W1, b1, H1Tp, H1Ti);
    colstats2x_kernel<<<256, 256, 0, stream>>>(H1Tp, H1Ti, 128, s1p, s1i);
    gemm2_kernel<<<320, 256, 0, stream>>>(H1Tp, H1Ti, W2, b2, s1p, s1i, g1, be1, H2Tp, H2Ti);
    colstats2x_kernel<<<128, 256, 0, stream>>>(H2Tp, H2Ti, 64, s2p, s2i);
    a2x_kernel<<<80, 256, 0, stream>>>(H2Tp, H2Ti, s2p, s2i, g2, be2,
                                       cw2, cb2, cw1, cb1, a2, a1);

    transpose_ps_kernel<<<1024, 256, 0, stream>>>(peers_style, PST);
    merge_kernel<<<16, 256, 0, stream>>>(candV, candI, a1, a2, w8, gidx, ncand);
    gather_kernel<<<128, 256, 0, stream>>>(w8, gidx, PST, out);
}

// Round 18
// 334.105 us; speedup vs baseline: 1.1638x; 1.0178x over previous
//
#include <hip/hip_runtime.h>
#include <math.h>

#define NROWS 4096
#define MCOLS 16384
#define CDIM  256

typedef _Float16 half8 __attribute__((ext_vector_type(8)));
typedef float f32x4 __attribute__((ext_vector_type(4)));
typedef float f32x16 __attribute__((ext_vector_type(16)));

static __device__ __forceinline__ float softplusf(float x) {
    return fmaxf(x, 0.0f) + log1pf(expf(-fabsf(x)));
}

// Classic top-8 update (merge phases only)
#define TOPK_UPDATE(BV, BI, WORST, WP, V, IDX)                                 \
    if ((V) < (WORST)) {                                                       \
        BV[WP] = (V); BI[WP] = (IDX);                                          \
        WORST = BV[0]; WP = 0;                                                 \
        _Pragma("unroll")                                                      \
        for (int _q = 1; _q < 8; ++_q)                                         \
            if (BV[_q] > WORST) { WORST = BV[_q]; WP = _q; }                   \
    }

// Hot-loop top-8: slot index in 3 LSBs; worst via max-tree; gate = min(tau, worst).
#define TOPK_FAST(BV, BI, WORST, GATE, TAU, V, IDX)                            \
    if ((V) < (GATE)) {                                                        \
        const int _wp = __float_as_int(WORST) & 7;                             \
        BV[_wp] = __uint_as_float((__float_as_uint(V) & ~7u) | (unsigned)_wp); \
        BI[_wp] = (IDX);                                                       \
        const float _m0 = fmaxf(fmaxf(BV[0], BV[1]), fmaxf(BV[2], BV[3]));     \
        const float _m1 = fmaxf(fmaxf(BV[4], BV[5]), fmaxf(BV[6], BV[7]));     \
        WORST = fmaxf(_m0, _m1);                                               \
        GATE = fminf(TAU, WORST);                                              \
    }

// ---------------------------------------------------------------------------
// Passthrough copy
// ---------------------------------------------------------------------------
__global__ __launch_bounds__(256)
void copy_kernel(const float4* __restrict__ src, float4* __restrict__ dst, int n4) {
    int i = blockIdx.x * blockDim.x + threadIdx.x;
    if (i < n4) dst[i] = src[i];
}

// ---------------------------------------------------------------------------
// fp32 [K=256][cols] -> fragment-ready fp16 hi/lo for 32x32x16 MFMA,
// PLUS per-tile column sumsq partials pp[ktile][col] (fused norms pass 1).
// Chunk (ct32*16 + kt)*64 + lane holds 8 halves:
//   element = x[col = ct32*32 + (lane&31)][k = kt*16 + (lane>>5)*8 + j]
// ---------------------------------------------------------------------------
__global__ __launch_bounds__(256)
void convert_kernel(const float* __restrict__ src, uint4* __restrict__ dhi,
                    uint4* __restrict__ dlo, int ncols, float* __restrict__ pp) {
    __shared__ float S[64][65];
    __shared__ float red[4][64];
    const int t = threadIdx.x;
    const int tilesPerRow = ncols >> 6;
    const int colbase = (blockIdx.x % tilesPerRow) << 6;
    const int ktile   = blockIdx.x / tilesPerRow;        // 0..3
    const int ktbase  = ktile << 6;
    const int b = colbase >> 12;
    const int pixbase = colbase & 4095;
    const float* sp = src + (size_t)b * (CDIM * 4096) + (size_t)ktbase * 4096 + pixbase;

    for (int i = t; i < 4096; i += 256) {
        int kk = i >> 6, cc = i & 63;
        S[kk][cc] = sp[kk * 4096 + cc];
    }
    __syncthreads();

    // fused norms partial: col = t&63, k-range (t>>6)*16..+16
    {
        const int cc = t & 63;
        const int kq = t >> 6;
        float s = 0.0f;
#pragma unroll
        for (int k = 0; k < 16; ++k) {
            const float v = S[kq * 16 + k][cc];
            s = fmaf(v, v, s);
        }
        red[kq][cc] = s;
    }
    __syncthreads();
    if (t < 64) {
        pp[(size_t)ktile * ncols + colbase + t] =
            red[0][t] + red[1][t] + red[2][t] + red[3][t];
    }

    const int l = t & 63;
#pragma unroll
    for (int s = 0; s < 2; ++s) {
        const int pid  = (t >> 6) + 4 * s;   // 0..7
        const int ct_l = pid & 1;
        const int kt_l = pid >> 1;
        const int c_l  = ct_l * 32 + (l & 31);
        const int k_l  = kt_l * 16 + ((l >> 5) << 3);
        half8 h, lo;
#pragma unroll
        for (int j = 0; j < 8; ++j) {
            float v = S[k_l + j][c_l];
            _Float16 hv = (_Float16)v;
            h[j]  = hv;
            lo[j] = (_Float16)(v - (float)hv);
        }
        const int ct_g = (colbase >> 5) + ct_l;
        const int kt_g = (ktbase >> 4) + kt_l;
        const size_t off = (size_t)(ct_g * 16 + kt_g) * 64 + l;
        dhi[off] = *reinterpret_cast<uint4*>(&h);
        dlo[off] = *reinterpret_cast<uint4*>(&lo);
    }
}

// ---------------------------------------------------------------------------
// Norms finish: normX[col] = sum of 4 ktile partials. Grid 80 x 256.
// ---------------------------------------------------------------------------
__global__ __launch_bounds__(256)
void norms_finish_kernel(const float* __restrict__ ppP, const float* __restrict__ ppI,
                         float* __restrict__ normP, float* __restrict__ normI) {
    const int i = blockIdx.x * 256 + threadIdx.x;
    if (i < MCOLS) {
        normP[i] = ppP[i] + ppP[MCOLS + i] + ppP[2 * MCOLS + i] + ppP[3 * MCOLS + i];
    } else if (i < MCOLS + NROWS) {
        const int c = i - MCOLS;
        normI[c] = ppI[c] + ppI[NROWS + c] + ppI[2 * NROWS + c] + ppI[3 * NROWS + c];
    }
}

// ---------------------------------------------------------------------------
// MFMA distance + per-row top-8 using 32x32x16 (R15 optimum config).
// Grid: 32 rowtiles (128 rows) * nsplit; 256 threads = 4 waves, 2 waves/SIMD.
// Wave w owns xi group ctg = rt*4+w (32 rows). Per iter: 32 xp cols.
// D layout: col = lane&31 -> xi row; row r: xp col = (r&3)+8*(r>>2)+4*(l>>5).
// Counted-vmcnt pipeline; v = 0.5*normP - dot domain; XCD cs map.
// ---------------------------------------------------------------------------
__global__ __launch_bounds__(256, 2)
void dist_topk_mfma(const uint4* __restrict__ xpBhi, const uint4* __restrict__ xpBlo,
                    const uint4* __restrict__ xiBhi, const uint4* __restrict__ xiBlo,
                    const float* __restrict__ normP,
                    float* __restrict__ candV, int* __restrict__ candI,
                    int nsplit) {
    __shared__ __align__(16) char Abuf[2][32768];   // [buf][hi 16KB][lo 16KB]
    __shared__ __align__(16) float nPl[2048];       // 0.5 * normP

    const int t = threadIdx.x;
    const int w = t >> 6;
    const int l = t & 63;
    int rt, cs;
    if (nsplit == 16) { cs = ((blockIdx.x & 7) << 1) | ((blockIdx.x >> 3) & 1); rt = blockIdx.x >> 4; }
    else              { cs = blockIdx.x & 7;                                    rt = blockIdx.x >> 3; }
    const int niter = (MCOLS / 32) / nsplit;
    const int span  = MCOLS / nsplit;
    const int colbase = cs * span;
    const int ncand = nsplit * 8;

    for (int i = t; i < span; i += 256) nPl[i] = 0.5f * normP[colbase + i];

    // xi fragments: group ctg = rt*4 + w covers rows rt*128 + w*32 .. +32
    uint4 bh[16], bl[16];
    const int ctg = rt * 4 + w;
#pragma unroll
    for (int kt = 0; kt < 16; ++kt) {
        bh[kt] = xiBhi[(size_t)(ctg * 16 + kt) * 64 + l];
        bl[kt] = xiBlo[(size_t)(ctg * 16 + kt) * 64 + l];
    }

    float bv[8]; int bi[8];
#pragma unroll
    for (int j = 0; j < 8; ++j) {
        bv[j] = __uint_as_float((0x7f7ffff8u) | (unsigned)j);
        bi[j] = -1;
    }
    float worst = bv[7], tau = bv[7], gate = bv[7];

    // staging: wave0 hi kt0-7, wave1 hi kt8-15, wave2 lo kt0-7, wave3 lo kt8-15
    const char* gb = (w >= 2) ? (const char*)xpBlo : (const char*)xpBhi;
    const char* srcBase = gb + (size_t)(cs * niter) * 16384 + (w & 1) * 8192 + l * 16;
    char* dbBase = &Abuf[0][(w >= 2 ? 16384 : 0) + (w & 1) * 8192];

    auto stage = [&](int it, int buf) {
        const char* src = srcBase + (size_t)it * 16384;
        char* db = dbBase + buf * 32768;
#pragma unroll
        for (int kt = 0; kt < 8; ++kt)
            __builtin_amdgcn_global_load_lds(
                (const __attribute__((address_space(1))) void*)(src + kt * 1024),
                (__attribute__((address_space(3))) void*)(db + kt * 1024),
                16, 0, 0);
    };

    stage(0, 0);
    asm volatile("s_waitcnt vmcnt(0)" ::: "memory");
    __builtin_amdgcn_s_barrier();

    for (int it = 0; it < niter; ++it) {
        if (it < niter - 1) {
            stage(it + 1, (it + 1) & 1);
            asm volatile("s_waitcnt vmcnt(8)" ::: "memory");
        } else {
            asm volatile("s_waitcnt vmcnt(0)" ::: "memory");
        }
        __builtin_amdgcn_s_barrier();
        __builtin_amdgcn_sched_barrier(0);

        const char* Ab = Abuf[it & 1];

        f32x16 a0, a1;
#pragma unroll
        for (int r = 0; r < 16; ++r) { a0[r] = 0.0f; a1[r] = 0.0f; }
        __builtin_amdgcn_s_setprio(1);
#pragma unroll
        for (int kt = 0; kt < 16; ++kt) {
            const half8 ah = *reinterpret_cast<const half8*>(Ab + kt * 1024 + l * 16);
            const half8 al = *reinterpret_cast<const half8*>(Ab + 16384 + kt * 1024 + l * 16);
            const half8 vh = *reinterpret_cast<const half8*>(&bh[kt]);
            const half8 vl = *reinterpret_cast<const half8*>(&bl[kt]);
            a0 = __builtin_amdgcn_mfma_f32_32x32x16_f16(ah, vh, a0, 0, 0, 0);
            a1 = __builtin_amdgcn_mfma_f32_32x32x16_f16(ah, vl, a1, 0, 0, 0);
            a0 = __builtin_amdgcn_mfma_f32_32x32x16_f16(al, vh, a0, 0, 0, 0);
        }
        __builtin_amdgcn_s_setprio(0);

        // dv[r]: xp col = it*32 + (r&3) + 8*(r>>2) + 4*(l>>5)
        float dv[16];
        const int lq = (l >> 5) << 2;
#pragma unroll
        for (int rq = 0; rq < 4; ++rq) {
            const float4 np4 = *reinterpret_cast<const float4*>(&nPl[it * 32 + rq * 8 + lq]);
            const float npv[4] = {np4.x, np4.y, np4.z, np4.w};
#pragma unroll
            for (int j = 0; j < 4; ++j) {
                const int r = rq * 4 + j;
                dv[r] = npv[j] - (a0[r] + a1[r]);
            }
        }
        float mn = dv[0];
#pragma unroll
        for (int r = 1; r < 16; ++r) mn = fminf(mn, dv[r]);
        const int ib = colbase + it * 32 + lq;
        if (__any(mn < gate)) {
#pragma unroll
            for (int r = 0; r < 16; ++r) {
                const int cb = ib + (r & 3) + 8 * (r >> 2);
                TOPK_FAST(bv, bi, worst, gate, tau, dv[r], cb);
            }
        }

        {
            tau = fminf(worst, __shfl_xor(worst, 32));
            gate = fminf(tau, worst);
        }

        __builtin_amdgcn_s_barrier();
    }

    // merge scratch aliased onto Abuf
    float* mVal = (float*)&Abuf[0][0];
    int*   mIdx = (int*)&Abuf[0][8192];

    __syncthreads();
#pragma unroll
    for (int j = 0; j < 8; ++j) { mVal[t * 8 + j] = bv[j]; mIdx[t * 8 + j] = bi[j]; }
    __syncthreads();
    if (t < 128) {
        const int t1 = ((t >> 5) << 6) + (t & 31);
        const int t2 = t1 + 32;
        float sv[8]; int si[8];
#pragma unroll
        for (int j = 0; j < 8; ++j) { sv[j] = 3.4e38f; si[j] = -1; }
        float wv = 3.4e38f; int wp = 0;
#pragma unroll
        for (int j = 0; j < 8; ++j) {
            const float v1 = mVal[t1 * 8 + j];
            TOPK_UPDATE(sv, si, wv, wp, v1, mIdx[t1 * 8 + j]);
            const float v2 = mVal[t2 * 8 + j];
            TOPK_UPDATE(sv, si, wv, wp, v2, mIdx[t2 * 8 + j]);
        }
        for (int a = 1; a < 8; ++a) {
            float v = sv[a]; int ii = si[a]; int b2 = a - 1;
            while (b2 >= 0 && sv[b2] > v) { sv[b2+1] = sv[b2]; si[b2+1] = si[b2]; --b2; }
            sv[b2+1] = v; si[b2+1] = ii;
        }
        const int row = rt * 128 + t;
#pragma unroll
        for (int j = 0; j < 8; ++j) {
            candV[row * ncand + cs * 8 + j] = sv[j];
            candI[row * ncand + cs * 8 + j] = si[j];
        }
    }
}

// ---------------------------------------------------------------------------
// MLP layer 1: CIN=256 (2x128 chunks), 64 outputs per block. Grid 640.
// ---------------------------------------------------------------------------
__global__ __launch_bounds__(256)
void gemm1_kernel(const float* __restrict__ Xp, const float* __restrict__ Xi,
                  const float* __restrict__ W, const float* __restrict__ bias,
                  float* __restrict__ outP, float* __restrict__ outI) {
    __shared__ __align__(16) float Wl[128][68];
    const int t = threadIdx.x;
    const bool isP = blockIdx.x < 512;
    const int bid  = isP ? blockIdx.x : blockIdx.x - 512;
    const float* X = isP ? Xp : Xi;
    const int rows = isP ? 16384 : 4096;
    float* outT = isP ? outP : outI;
    const int rowblk = bid >> 1;
    const int ch     = bid & 1;

    const int r   = rowblk * 64 + (t & 63);
    const int kgb = (t >> 6) * 16;

    float acc[16];
#pragma unroll
    for (int q = 0; q < 16; ++q) acc[q] = 0.0f;

    for (int half = 0; half < 2; ++half) {
        __syncthreads();
        for (int i = t; i < 128 * 64; i += 256) {
            int k = i >> 7, c = i & 127;
            Wl[c][k] = W[(ch * 64 + k) * 256 + half * 128 + c];
        }
        __syncthreads();
#pragma unroll 2
        for (int c = 0; c < 128; ++c) {
            const int cg = half * 128 + c;
            const float x = X[(r >> 12) * (CDIM * 4096) + cg * 4096 + (r & 4095)];
#pragma unroll
            for (int q = 0; q < 4; ++q) {
                const float4 wv = *reinterpret_cast<const float4*>(&Wl[c][kgb + 4 * q]);
                acc[4 * q + 0] = fmaf(x, wv.x, acc[4 * q + 0]);
                acc[4 * q + 1] = fmaf(x, wv.y, acc[4 * q + 1]);
                acc[4 * q + 2] = fmaf(x, wv.z, acc[4 * q + 2]);
                acc[4 * q + 3] = fmaf(x, wv.w, acc[4 * q + 3]);
            }
        }
    }
#pragma unroll
    for (int q = 0; q < 16; ++q) {
        const int k = ch * 64 + kgb + q;
        outT[k * rows + r] = acc[q] + bias[k];
    }
}

// ---------------------------------------------------------------------------
// MLP layer 2 (CIN=128, COUT=64, BN+ReLU on input). Grid 320.
// ---------------------------------------------------------------------------
__global__ __launch_bounds__(256)
void gemm2_kernel(const float* __restrict__ Hp, const float* __restrict__ Hi,
                  const float* __restrict__ W, const float* __restrict__ bias,
                  const float* __restrict__ statsP, const float* __restrict__ statsI,
                  const float* __restrict__ g, const float* __restrict__ be,
                  float* __restrict__ outP, float* __restrict__ outI) {
    __shared__ __align__(16) float Wl[128][68];
    __shared__ float scL[128], shL[128];
    const int t = threadIdx.x;
    const bool isP = blockIdx.x < 256;
    const float* X = isP ? Hp : Hi;
    const float* stats = isP ? statsP : statsI;
    const float invDenom = isP ? (1.0f / 16384.0f) : (1.0f / 4096.0f);
    const int rows = isP ? 16384 : 4096;
    const int blk  = isP ? blockIdx.x : blockIdx.x - 256;
    float* outT = isP ? outP : outI;

    for (int i = t; i < 128 * 64; i += 256) {
        int k = i >> 7, c = i & 127;
        Wl[c][k] = W[k * 128 + c];
    }
    if (t < 128) {
        float mean = stats[t] * invDenom;
        float var  = stats[128 + t] * invDenom - mean * mean;
        float sc   = rsqrtf(var + 1e-5f) * g[t];
        scL[t] = sc;
        shL[t] = be[t] - mean * sc;
    }
    __syncthreads();

    const int r   = blk * 64 + (t & 63);
    const int chb = (t >> 6) * 16;

    float acc[16];
#pragma unroll
    for (int q = 0; q < 16; ++q) acc[q] = 0.0f;

#pragma unroll 2
    for (int c = 0; c < 128; ++c) {
        float x = X[c * rows + r];
        x = fmaxf(fmaf(x, scL[c], shL[c]), 0.0f);
#pragma unroll
        for (int q = 0; q < 4; ++q) {
            const float4 wv = *reinterpret_cast<const float4*>(&Wl[c][chb + 4 * q]);
            acc[4 * q + 0] = fmaf(x, wv.x, acc[4 * q + 0]);
            acc[4 * q + 1] = fmaf(x, wv.y, acc[4 * q + 1]);
            acc[4 * q + 2] = fmaf(x, wv.z, acc[4 * q + 2]);
            acc[4 * q + 3] = fmaf(x, wv.w, acc[4 * q + 3]);
        }
    }
#pragma unroll
    for (int q = 0; q < 16; ++q) {
        const int k = chb + q;
        outT[k * rows + r] = acc[q] + bias[k];
    }
}

// ---------------------------------------------------------------------------
// Column stats for peers+input in one launch. Grid = 2*C.
// ---------------------------------------------------------------------------
__global__ __launch_bounds__(256)
void colstats2x_kernel(const float* __restrict__ Hp, const float* __restrict__ Hi,
                       int C, float* __restrict__ statsP, float* __restrict__ statsI) {
    __shared__ float rs[256], rq[256];
    const bool isP = blockIdx.x < (unsigned)C;
    const int c = isP ? blockIdx.x : blockIdx.x - C;
    const float* H = isP ? Hp : Hi;
    const int rows = isP ? 16384 : 4096;
    float* stats = isP ? statsP : statsI;
    const int t = threadIdx.x;
    float s = 0.0f, q = 0.0f;
    for (int r = t; r < rows; r += 256) {
        float v = H[c * rows + r];
        s += v;
        q = fmaf(v, v, q);
    }
    rs[t] = s; rq[t] = q;
    __syncthreads();
    for (int st = 128; st > 0; st >>= 1) {
        if (t < st) { rs[t] += rs[t + st]; rq[t] += rq[t + st]; }
        __syncthreads();
    }
    if (t == 0) { stats[c] = rs[0]; stats[C + c] = rq[0]; }
}

// ---------------------------------------------------------------------------
// a-scores for peers+input in one launch. Grid = 80.
// ---------------------------------------------------------------------------
__global__ __launch_bounds__(256)
void a2x_kernel(const float* __restrict__ Hp, const float* __restrict__ Hi,
                const float* __restrict__ statsP, const float* __restrict__ statsI,
                const float* __restrict__ g, const float* __restrict__ be,
                const float* __restrict__ cwP, const float* __restrict__ cbP,
                const float* __restrict__ cwI, const float* __restrict__ cbI,
                float* __restrict__ aP, float* __restrict__ aI) {
    __shared__ float scL[64], shL[64], cwL[64];
    const bool isP = blockIdx.x < 64;
    const float* H = isP ? Hp : Hi;
    const float* stats = isP ? statsP : statsI;
    const float* cw = isP ? cwP : cwI;
    const float* cb = isP ? cbP : cbI;
    float* aout = isP ? aP : aI;
    const int rows = isP ? 16384 : 4096;
    const float invDenom = isP ? (1.0f / 16384.0f) : (1.0f / 4096.0f);
    const int blk = isP ? blockIdx.x : blockIdx.x - 64;
    const int t = threadIdx.x;
    if (t < 64) {
        float mean = stats[t] * invDenom;
        float var  = stats[64 + t] * invDenom - mean * mean;
        float sc   = rsqrtf(var + 1e-5f) * g[t];
        scL[t] = sc;
        shL[t] = be[t] - mean * sc;
        cwL[t] = cw[t];
    }
    __syncthreads();
    const int row = blk * 256 + t;
    if (row < rows) {
        float a = 0.0f;
        for (int c = 0; c < 64; ++c) {
            float v = H[c * rows + row];
            a += fmaxf(fmaf(v, scL[c], shL[c]), 0.0f) * cwL[c];
        }
        aout[row] = a + cb[0];
    }
}

// ---------------------------------------------------------------------------
// Merge candidates -> per-row softmax weights + gather base addresses.
// ---------------------------------------------------------------------------
__global__ __launch_bounds__(256)
void merge_kernel(const float* __restrict__ candV, const int* __restrict__ candI,
                  const float* __restrict__ a1, const float* __restrict__ a2,
                  float* __restrict__ w8, int* __restrict__ gidx, int ncand) {
    const int row = blockIdx.x * 256 + threadIdx.x;
    float sv[8]; int si[8];
#pragma unroll
    for (int j = 0; j < 8; ++j) { sv[j] = 3.4e38f; si[j] = 0; }
    float w2 = 3.4e38f; int wp = 0;
    for (int k = 0; k < ncand; ++k) {
        const float v = candV[row * ncand + k];
        TOPK_UPDATE(sv, si, w2, wp, v, candI[row * ncand + k]);
    }
    for (int a = 1; a < 8; ++a) {
        float v = sv[a]; int ii = si[a]; int b = a - 1;
        while (b >= 0 && sv[b] > v) { sv[b + 1] = sv[b]; si[b + 1] = si[b]; --b; }
        sv[b + 1] = v; si[b + 1] = ii;
    }
    const float kth = sv[4];
    int cnt = 5;
    while (cnt < 8 && sv[cnt] <= kth) ++cnt;

    const float arow = a1[row];
    float s[8], e[8];
    float mx = -1e30f;
#pragma unroll
    for (int j = 0; j < 8; ++j) s[j] = 0.0f;
    for (int j = 0; j < cnt; ++j) {
        s[j] = softplusf(arow + a2[si[j]]);
        mx = fmaxf(mx, s[j]);
    }
    float Z = 0.0f;
    for (int j = 0; j < 8; ++j) {
        e[j] = (j < cnt) ? expf(s[j] - mx) : 0.0f;
        Z += e[j];
    }
#pragma unroll
    for (int j = 0; j < 8; ++j) {
        const int ix = (j < cnt) ? si[j] : si[0];
        w8[row * 8 + j]   = e[j] / Z;
        gidx[row * 8 + j] = (ix >> 12) * (CDIM * 4096) + (ix & 4095);
    }
}

// ---------------------------------------------------------------------------
// Gather: out[(256+c)*4096 + n] = sum_j w8[n][j] * PS[gidx[n][j] + c*4096].
// Grid 1024 = 64 rowtiles x 16 channel chunks; thread: 1 row x 4 channels.
// ---------------------------------------------------------------------------
__global__ __launch_bounds__(256)
void gather_kernel(const float* __restrict__ w8, const int* __restrict__ gidx,
                   const float* __restrict__ PS, float* __restrict__ dout) {
    const int t = threadIdx.x;
    const int rtile = blockIdx.x >> 4;
    const int chunk = blockIdx.x & 15;
    const int row = rtile * 64 + (t & 63);
    const int c0  = chunk * 16 + (t >> 6) * 4;

    float w[8]; int ab[8];
#pragma unroll
    for (int j = 0; j < 8; ++j) { w[j] = w8[row * 8 + j]; ab[j] = gidx[row * 8 + j]; }

#pragma unroll
    for (int cc = 0; cc < 4; ++cc) {
        const int c = c0 + cc;
        float acc = 0.0f;
#pragma unroll
        for (int j = 0; j < 8; ++j) acc += w[j] * PS[ab[j] + c * 4096];
        dout[(CDIM + c) * 4096 + row] = acc;
    }
}

// ---------------------------------------------------------------------------
extern "C" void kernel_launch(void* const* d_in, const int* in_sizes, int n_in,
                              void* d_out, int out_size, void* d_ws, size_t ws_size,
                              hipStream_t stream) {
    const float* inp_cont    = (const float*)d_in[0];
    const float* peers_cont  = (const float*)d_in[2];
    const float* peers_style = (const float*)d_in[3];
    const float* W1  = (const float*)d_in[4];
    const float* b1  = (const float*)d_in[5];
    const float* g1  = (const float*)d_in[6];
    const float* be1 = (const float*)d_in[7];
    const float* W2  = (const float*)d_in[8];
    const float* b2  = (const float*)d_in[9];
    const float* g2  = (const float*)d_in[10];
    const float* be2 = (const float*)d_in[11];
    const float* cw1 = (const float*)d_in[12];
    const float* cb1 = (const float*)d_in[13];
    const float* cw2 = (const float*)d_in[14];
    const float* cb2 = (const float*)d_in[15];
    float* out = (float*)d_out;
    char*  wsb = (char*)d_ws;

    int nsplit;
    if      (ws_size >= (size_t)25400000) nsplit = 16;
    else if (ws_size >= (size_t)23300000) nsplit = 8;
    else return;
    const int ncand = nsplit * 8;
    const size_t candBytes = (size_t)NROWS * ncand * 4;

    // workspace layout (bytes)
    uint4* xpBhi = (uint4*)(wsb + 0);                    //  8 MB
    uint4* xpBlo = (uint4*)(wsb + 8388608);              //  8 MB
    uint4* xiBhi = (uint4*)(wsb + 16777216);             //  2 MB
    uint4* xiBlo = (uint4*)(wsb + 18874368);             //  2 MB
    float* normP = (float*)(wsb + 20971520);             //  64 KB
    float* normI = (float*)(wsb + 21037056);             //  16 KB
    float* candV = (float*)(wsb + 21053440);             //  candBytes
    int*   candI = (int*)  (wsb + 21053440 + candBytes); //  candBytes
    char*  tail  = wsb + 21053440 + 2 * candBytes;
    float* a2    = (float*)(tail);                       //  64 KB
    float* a1    = (float*)(tail + 65536);               //  16 KB
    float* s1p   = (float*)(tail + 81920);               //  1 KB
    float* s1i   = (float*)(tail + 82944);               //  1 KB
    float* s2p   = (float*)(tail + 83968);               //  512
    float* s2i   = (float*)(tail + 84480);               //  512
    // pp partials alias candV region (consumed by norms_finish before dist writes)
    float* ppP   = candV;                                // 4*16384 floats = 256 KB
    float* ppI   = candV + 4 * MCOLS;                    // 4*4096 floats  =  64 KB
    // Aliased AFTER dist kernel completes:
    float* H1Tp  = (float*)(wsb + 0);                    // 8 MB
    float* H2Tp  = (float*)(wsb + 8388608);              // 4 MB
    float* H1Ti  = (float*)(wsb + 16777216);             // 2 MB
    float* H2Ti  = (float*)(wsb + 18874368);             // 1 MB (ends 19922944)
    float* w8    = (float*)(wsb + 19922944);             // 128 KB
    int*   gidx  = (int*)  (wsb + 20054016);             // 128 KB

    copy_kernel<<<1024, 256, 0, stream>>>((const float4*)inp_cont, (float4*)out, 262144);
    convert_kernel<<<256, 256, 0, stream>>>(inp_cont, xiBhi, xiBlo, 4096, ppI);
    convert_kernel<<<1024, 256, 0, stream>>>(peers_cont, xpBhi, xpBlo, 16384, ppP);
    norms_finish_kernel<<<80, 256, 0, stream>>>(ppP, ppI, normP, normI);

    dist_topk_mfma<<<32 * nsplit, 256, 0, stream>>>(xpBhi, xpBlo, xiBhi, xiBlo,
                                                    normP, candV, candI, nsplit);

    gemm1_kernel<<<640, 256, 0, stream>>>(peers_cont, inp_cont, W1, b1, H1Tp, H1Ti);
    colstats2x_kernel<<<256, 256, 0, stream>>>(H1Tp, H1Ti, 128, s1p, s1i);
    gemm2_kernel<<<320, 256, 0, stream>>>(H1Tp, H1Ti, W2, b2, s1p, s1i, g1, be1, H2Tp, H2Ti);
    colstats2x_kernel<<<128, 256, 0, stream>>>(H2Tp, H2Ti, 64, s2p, s2i);
    a2x_kernel<<<80, 256, 0, stream>>>(H2Tp, H2Ti, s2p, s2i, g2, be2,
                                       cw2, cb2, cw1, cb1, a2, a1);

    merge_kernel<<<16, 256, 0, stream>>>(candV, candI, a1, a2, w8, gidx, ncand);
    gather_kernel<<<1024, 256, 0, stream>>>(w8, gidx, peers_style, out);
}